// Round 13
// baseline (120.184 us; speedup 1.0000x reference)
//
#include <hip/hip_runtime.h>

#define NMOL   32
#define NATOM  512
#define NPAIR  32768
#define NB     64
#define HIDDEN 256
#define TOTNATOM (NMOL * NATOM)
#define NSUB   8
#define CAP8   16    // records per (atom, sub-block)
#define ABLK   8     // atoms per gnn block
#define NGNN   (TOTNATOM / ABLK)   // 2048 blocks
#define SLOTS  128   // LDS record slots per atom (= NSUB*CAP8)

// ---------------------------------------------------------------------------
// K1 scatter: 256 blocks (mol x sub) x 1024 thr, 4 pairs/thread.
// cart+species staged in LDS; LDS-private counters -> per-block record
// segments; zero cross-XCD atomics. (Unchanged from R12 except dipole-zero
// removed -- dipfinal now overwrites.)
// ---------------------------------------------------------------------------
__global__ __launch_bounds__(1024) void scatter_kernel(
    const float* __restrict__ cart, const float* __restrict__ shifts,
    const int* __restrict__ species, const int* __restrict__ atom_index,
    unsigned* __restrict__ cnt8, float2* __restrict__ rec,
    float* __restrict__ tv_part)
{
    __shared__ float    tv_sc[NATOM * 3];   // 6 KB
    __shared__ float    s_cart[NATOM * 3];  // 6 KB
    __shared__ int      s_sp[NATOM];        // 2 KB
    __shared__ unsigned lcnt[NATOM];        // 2 KB
    const int tid = threadIdx.x;
    const int b   = blockIdx.x;
    const int mol = b >> 3;
    const int sub = b & 7;

    const float* cm = cart + (size_t)mol * NATOM * 3;
    const int*   sp = species + (size_t)mol * NATOM;
    for (int i = tid; i < NATOM * 3; i += 1024) { tv_sc[i] = 0.f; s_cart[i] = cm[i]; }
    if (tid < NATOM) { lcnt[tid] = 0u; s_sp[tid] = sp[tid]; }
    __syncthreads();

    const int* ai0 = atom_index + (size_t)mol * NPAIR;
    const int* ai1 = ai0 + (size_t)NMOL * NPAIR;
    const float* sh = shifts + (size_t)mol * NPAIR * 3;
    const int base = sub * 4096;

#pragma unroll
    for (int k = 0; k < 4; ++k) {
        const int p  = base + k * 1024 + tid;
        const int i0 = ai0[p];
        const int i1 = ai1[p];
        const float sx = sh[p * 3 + 0], sy = sh[p * 3 + 1], sz = sh[p * 3 + 2];
        if (!(sx > -1e10f && sy > -1e10f && sz > -1e10f)) continue;  // masked
        const float dx = s_cart[i0 * 3 + 0] - s_cart[i1 * 3 + 0] + sx;
        const float dy = s_cart[i0 * 3 + 1] - s_cart[i1 * 3 + 1] + sy;
        const float dz = s_cart[i0 * 3 + 2] - s_cart[i1 * 3 + 2] + sz;
        unsafeAtomicAdd(&tv_sc[i0 * 3 + 0], dx);        // ds_add_f32
        unsafeAtomicAdd(&tv_sc[i0 * 3 + 1], dy);
        unsafeAtomicAdd(&tv_sc[i0 * 3 + 2], dz);
        const float d = sqrtf(dx * dx + dy * dy + dz * dz + 1e-12f);
        if (d < 5.0f) {
            const float fc = 0.5f * (__cosf(0.62831853071795864769f * d) + 1.f);
            // pack spc into fc's low 3 mantissa bits (<=2^-20 rel perturbation)
            const unsigned fb = (__float_as_uint(fc) & ~7u) | (unsigned)s_sp[i1];
            const unsigned pos = atomicAdd(&lcnt[i0], 1u);   // LDS, native
            if (pos < CAP8)
                rec[((size_t)b * NATOM + i0) * CAP8 + pos] =
                    make_float2(d, __uint_as_float(fb));
        }
    }
    __syncthreads();

    if (tid < NATOM) cnt8[((size_t)mol * NATOM + tid) * NSUB + sub] = lcnt[tid];
    float* tg = tv_part + (size_t)b * NATOM * 3;
    for (int i = tid; i < NATOM * 3; i += 1024) tg[i] = tv_sc[i];
}

// ---------------------------------------------------------------------------
// K2 gnn: 2048 blocks x 256 thr, 8 atoms/block (8 blocks/CU -- R12 was
// grid-capped at 4/CU, occupancy 24%).
// NN PHASE IS K-CHUNKED (the R12 fix): thread j holds only w1c[16] (one
// K-quarter of its W1 column) + h[8] accumulators, ~30 live VGPR. W1 read
// once per thread. R5-R12's w1r[64] never fit the ~52-VGPR budget the
// compiler insists on; it silently re-loaded W1 per atom (~1 GB L2/dispatch,
// the persistent hidden ~40us that dominated every total since R5).
// ---------------------------------------------------------------------------
__global__ __launch_bounds__(256) void gnn_kernel(
    const unsigned* __restrict__ cnt8, const float2* __restrict__ rec,
    const float* __restrict__ centers, const float* __restrict__ widths,
    const float* __restrict__ c_emb, const float* __restrict__ tv_part,
    const float* __restrict__ W1, const float* __restrict__ b1,
    const float* __restrict__ W2, const float* __restrict__ b2,
    float* __restrict__ dip_part)
{
    __shared__ float    cemb[8 * NB];          // 2 KB
    __shared__ float2   list[ABLK][SLOTS];     // 8 KB
    __shared__ unsigned scnt[ABLK][NSUB];
    __shared__ unsigned soff[ABLK][NSUB];
    __shared__ unsigned mtot[ABLK];
    __shared__ float    dens_l[ABLK][NB];      // 2 KB
    __shared__ float    tv_l[ABLK * 3];
    __shared__ float    part[4][ABLK];

    const int tid = threadIdx.x;
    const int a0  = blockIdx.x * ABLK;
    const int mol = a0 >> 9;
    const int ra0 = a0 & 511;

    for (int i = tid; i < 8 * NB; i += 256) cemb[i] = c_emb[i];
    if (tid < ABLK * NSUB) {
        const int al = tid >> 3, s = tid & 7;
        scnt[al][s] = cnt8[(size_t)(a0 + al) * NSUB + s];   // coalesced
    }
    __syncthreads();

    if (tid < ABLK) {    // per-atom prefix over 8 segment counts + zero-pad
        unsigned o = 0;
#pragma unroll
        for (int s = 0; s < NSUB; ++s) {
            soff[tid][s] = o;
            o += min(scnt[tid][s], (unsigned)CAP8);
        }
        const unsigned mp = (o + 7u) & ~7u;    // pad to multiple of 8
        mtot[tid] = mp;
        for (unsigned k = o; k < mp; ++k) list[tid][k] = make_float2(0.f, 0.f);
    }
    __syncthreads();

    {   // 256-thread parallel segment copy: 4 threads per (atom, sub) segment
        const int seg = tid >> 2;              // 0..63
        const int prt = tid & 3;
        const int al = seg >> 3, s = seg & 7;
        const int n = (int)min(scnt[al][s], (unsigned)CAP8);
        const float2* src = rec + ((size_t)(mol * NSUB + s) * NATOM + (ra0 + al)) * CAP8;
        float2* dst = &list[al][soff[al][s]];
        const int k0 = prt * 4, k1 = min(k0 + 4, n);
        for (int k = k0; k < k1; ++k) dst[k] = src[k];
    }
    if (tid < ABLK * 3) {                      // tv: sum the 8 block-partials
        const int al = tid / 3, c = tid - al * 3;
        float s = 0.f;
#pragma unroll
        for (int sb = 0; sb < NSUB; ++sb)
            s += tv_part[((size_t)(mol * NSUB + sb) * NATOM + (ra0 + al)) * 3 + c];
        tv_l[al * 3 + c] = s;
    }
    __syncthreads();

    const int lane = tid & 63;
    const int wave = tid >> 6;

    // ---- gather compute: wave handles 2 atoms, dual accumulator ----
    {
        const float cb   = centers[lane];
        const float nwb2 = -widths[lane] * 1.4426950408889634f;   // fold log2(e)

#define REC1(A, dv, fv) { const unsigned f_ = __float_as_uint(fv);           \
        const float t_ = (dv) - cb;                                          \
        A = fmaf(exp2f(nwb2 * t_ * t_) * __uint_as_float(f_ & ~7u),          \
                 cemb[((f_ & 7u) << 6) | lane], A); }

        for (int al = wave; al < ABLK; al += 4) {
            const int m = (int)mtot[al];
            const float4* l4 = reinterpret_cast<const float4*>(list[al]);
            float acc0 = 0.f, acc1 = 0.f;
            for (int j = 0; j < m; j += 8) {   // 8 records per chunk
                const float4 q0 = l4[(j >> 1) + 0];
                const float4 q1 = l4[(j >> 1) + 1];
                const float4 q2 = l4[(j >> 1) + 2];
                const float4 q3 = l4[(j >> 1) + 3];
                REC1(acc0, q0.x, q0.y) REC1(acc1, q0.z, q0.w)
                REC1(acc0, q1.x, q1.y) REC1(acc1, q1.z, q1.w)
                REC1(acc0, q2.x, q2.y) REC1(acc1, q2.z, q2.w)
                REC1(acc0, q3.x, q3.y) REC1(acc1, q3.z, q3.w)
            }
            dens_l[al][lane] = acc0 + acc1;
        }
#undef REC1
    }
    __syncthreads();

    // ---- nn: thread = hidden unit, K-CHUNKED (w1c[16] + h[8] live) ----
    {
        const int j = tid;
        float h[ABLK];
#pragma unroll
        for (int a = 0; a < ABLK; ++a) h[a] = 0.f;

#pragma unroll
        for (int kc = 0; kc < 4; ++kc) {
            float w1c[16];
#pragma unroll
            for (int q = 0; q < 16; ++q)
                w1c[q] = W1[(kc * 16 + q) * HIDDEN + j];   // coalesced, once
#pragma unroll
            for (int a = 0; a < ABLK; ++a) {
                const float4* row4 = reinterpret_cast<const float4*>(dens_l[a]) + kc * 4;
                float h0 = 0.f, h1 = 0.f, h2 = 0.f, h3 = 0.f;
#pragma unroll
                for (int q4 = 0; q4 < 4; ++q4) {           // ds_read_b128 broadcast
                    const float4 v = row4[q4];
                    h0 = fmaf(v.x, w1c[q4 * 4 + 0], h0);
                    h1 = fmaf(v.y, w1c[q4 * 4 + 1], h1);
                    h2 = fmaf(v.z, w1c[q4 * 4 + 2], h2);
                    h3 = fmaf(v.w, w1c[q4 * 4 + 3], h3);
                }
                h[a] += (h0 + h1) + (h2 + h3);
            }
        }

        const float b1v = b1[j];
        const float w2v = W2[j];
#pragma unroll
        for (int a = 0; a < ABLK; ++a) {
            const float hv = h[a] + b1v;
            float con = (hv / (1.f + __expf(-hv))) * w2v;   // silu * W2
#pragma unroll
            for (int off = 32; off; off >>= 1) con += __shfl_down(con, off);
            if (lane == 0) part[wave][a] = con;
        }
        __syncthreads();

        if (tid < ABLK) {
            const int a = tid;
            const float out = part[0][a] + part[1][a] + part[2][a] + part[3][a] + b2[0];
            float px = out * tv_l[a * 3 + 0];
            float py = out * tv_l[a * 3 + 1];
            float pz = out * tv_l[a * 3 + 2];
#pragma unroll
            for (int off = 4; off; off >>= 1) {
                px += __shfl_down(px, off, 8);
                py += __shfl_down(py, off, 8);
                pz += __shfl_down(pz, off, 8);
            }
            if (a == 0) {
                dip_part[blockIdx.x * 3 + 0] = px;   // plain store, no atomics
                dip_part[blockIdx.x * 3 + 1] = py;
                dip_part[blockIdx.x * 3 + 2] = pz;
            }
        }
    }
}

// ---------------------------------------------------------------------------
// K3 dipfinal: reduce 64 block-partials per molecule (96 outputs).
// ---------------------------------------------------------------------------
__global__ __launch_bounds__(128) void dipfinal_kernel(
    const float* __restrict__ dip_part, float* __restrict__ dipole)
{
    const int t = threadIdx.x;
    if (t < NMOL * 3) {
        const int m = t / 3, c = t - m * 3;
        const int bpm = NGNN / NMOL;            // 64 blocks per molecule
        float s = 0.f;
        for (int k = 0; k < bpm; ++k) s += dip_part[(m * bpm + k) * 3 + c];
        dipole[t] = s;
    }
}

// ---------------------------------------------------------------------------
extern "C" void kernel_launch(void* const* d_in, const int* in_sizes, int n_in,
                              void* d_out, int out_size, void* d_ws, size_t ws_size,
                              hipStream_t stream)
{
    const float* cart       = (const float*)d_in[0];
    const float* shifts     = (const float*)d_in[1];
    const float* centers    = (const float*)d_in[2];
    const float* widths     = (const float*)d_in[3];
    const float* c_emb      = (const float*)d_in[4];
    const float* W1         = (const float*)d_in[5];
    const float* b1         = (const float*)d_in[6];
    const float* W2         = (const float*)d_in[7];
    const float* b2         = (const float*)d_in[8];
    const int*   species    = (const int*)d_in[10];
    const int*   atom_index = (const int*)d_in[11];

    // ws: tv_part(1.5MB) | cnt8(512KB) | dip_part(24KB) | rec(16MB)
    float*    tv_part  = (float*)d_ws;
    unsigned* cnt8     = (unsigned*)(tv_part + (size_t)NMOL * NSUB * NATOM * 3);
    float*    dip_part = (float*)(cnt8 + (size_t)TOTNATOM * NSUB);
    float2*   rec      = (float2*)(dip_part + (size_t)NGNN * 3);
    float*    dipole   = (float*)d_out;

    hipLaunchKernelGGL(scatter_kernel, dim3(NMOL * NSUB), dim3(1024), 0, stream,
                       cart, shifts, species, atom_index, cnt8, rec, tv_part);
    hipLaunchKernelGGL(gnn_kernel, dim3(NGNN), dim3(256), 0, stream,
                       cnt8, rec, centers, widths, c_emb, tv_part,
                       W1, b1, W2, b2, dip_part);
    hipLaunchKernelGGL(dipfinal_kernel, dim3(1), dim3(128), 0, stream,
                       dip_part, dipole);
}

// Round 14
// 54.902 us; speedup vs baseline: 2.1891x; 2.1891x over previous
//
#include <hip/hip_runtime.h>

#define NMOL   32
#define NATOM  512
#define NPAIR  32768
#define NB     64
#define HIDDEN 256
#define TOTNATOM (NMOL * NATOM)
#define NSUB   8
#define CAP8   16    // records per (atom, sub-block)
#define ABLK   8     // atoms per gather block
#define SLOTS  128   // LDS record slots per atom

typedef __attribute__((ext_vector_type(8))) short bf16x8;
typedef __attribute__((ext_vector_type(4))) float f32x4;

__device__ __forceinline__ unsigned short f2bf(float x) {   // RNE f32->bf16
    unsigned u = __float_as_uint(x);
    u += 0x7FFFu + ((u >> 16) & 1u);
    return (unsigned short)(u >> 16);
}

// ---------------------------------------------------------------------------
// K1 scatter: unchanged (R12/R13). 256 blocks x 1024 thr; LDS-private
// counters, per-block record segments, zero cross-XCD atomics.
// ---------------------------------------------------------------------------
__global__ __launch_bounds__(1024) void scatter_kernel(
    const float* __restrict__ cart, const float* __restrict__ shifts,
    const int* __restrict__ species, const int* __restrict__ atom_index,
    unsigned* __restrict__ cnt8, float2* __restrict__ rec,
    float* __restrict__ tv_part)
{
    __shared__ float    tv_sc[NATOM * 3];   // 6 KB
    __shared__ float    s_cart[NATOM * 3];  // 6 KB
    __shared__ int      s_sp[NATOM];        // 2 KB
    __shared__ unsigned lcnt[NATOM];        // 2 KB
    const int tid = threadIdx.x;
    const int b   = blockIdx.x;
    const int mol = b >> 3;
    const int sub = b & 7;

    const float* cm = cart + (size_t)mol * NATOM * 3;
    const int*   sp = species + (size_t)mol * NATOM;
    for (int i = tid; i < NATOM * 3; i += 1024) { tv_sc[i] = 0.f; s_cart[i] = cm[i]; }
    if (tid < NATOM) { lcnt[tid] = 0u; s_sp[tid] = sp[tid]; }
    __syncthreads();

    const int* ai0 = atom_index + (size_t)mol * NPAIR;
    const int* ai1 = ai0 + (size_t)NMOL * NPAIR;
    const float* sh = shifts + (size_t)mol * NPAIR * 3;
    const int base = sub * 4096;

#pragma unroll
    for (int k = 0; k < 4; ++k) {
        const int p  = base + k * 1024 + tid;
        const int i0 = ai0[p];
        const int i1 = ai1[p];
        const float sx = sh[p * 3 + 0], sy = sh[p * 3 + 1], sz = sh[p * 3 + 2];
        if (!(sx > -1e10f && sy > -1e10f && sz > -1e10f)) continue;  // masked
        const float dx = s_cart[i0 * 3 + 0] - s_cart[i1 * 3 + 0] + sx;
        const float dy = s_cart[i0 * 3 + 1] - s_cart[i1 * 3 + 1] + sy;
        const float dz = s_cart[i0 * 3 + 2] - s_cart[i1 * 3 + 2] + sz;
        unsafeAtomicAdd(&tv_sc[i0 * 3 + 0], dx);        // ds_add_f32
        unsafeAtomicAdd(&tv_sc[i0 * 3 + 1], dy);
        unsafeAtomicAdd(&tv_sc[i0 * 3 + 2], dz);
        const float d = sqrtf(dx * dx + dy * dy + dz * dz + 1e-12f);
        if (d < 5.0f) {
            const float fc = 0.5f * (__cosf(0.62831853071795864769f * d) + 1.f);
            const unsigned fb = (__float_as_uint(fc) & ~7u) | (unsigned)s_sp[i1];
            const unsigned pos = atomicAdd(&lcnt[i0], 1u);   // LDS, native
            if (pos < CAP8)
                rec[((size_t)b * NATOM + i0) * CAP8 + pos] =
                    make_float2(d, __uint_as_float(fb));
        }
    }
    __syncthreads();

    if (tid < NATOM) cnt8[((size_t)mol * NATOM + tid) * NSUB + sub] = lcnt[tid];
    float* tg = tv_part + (size_t)b * NATOM * 3;
    for (int i = tid; i < NATOM * 3; i += 1024) tg[i] = tv_sc[i];
}

// ---------------------------------------------------------------------------
// K2 gather: 2048 blocks x 256 thr, 8 atoms/block. Standalone (lean VGPR;
// fusing with nn forced pathological allocations in R8/R12/R13).
// Emits density as BF16 rows (feeds nn's MFMA A-fragments directly).
// ---------------------------------------------------------------------------
__global__ __launch_bounds__(256) void gather_kernel(
    const unsigned* __restrict__ cnt8, const float2* __restrict__ rec,
    const float* __restrict__ centers, const float* __restrict__ widths,
    const float* __restrict__ c_emb, const float* __restrict__ tv_part,
    unsigned short* __restrict__ dens_bf, float* __restrict__ tvv)
{
    __shared__ float    cemb[8 * NB];          // 2 KB
    __shared__ float2   list[ABLK][SLOTS];     // 8 KB
    __shared__ unsigned scnt[ABLK][NSUB];
    __shared__ unsigned soff[ABLK][NSUB];
    __shared__ unsigned mtot[ABLK];

    const int tid = threadIdx.x;
    const int a0  = blockIdx.x * ABLK;
    const int mol = a0 >> 9;
    const int ra0 = a0 & 511;

    for (int i = tid; i < 8 * NB; i += 256) cemb[i] = c_emb[i];
    if (tid < ABLK * NSUB) {
        const int al = tid >> 3, s = tid & 7;
        scnt[al][s] = cnt8[(size_t)(a0 + al) * NSUB + s];   // coalesced
    }
    __syncthreads();

    if (tid < ABLK) {    // per-atom prefix over 8 segment counts + zero-pad
        unsigned o = 0;
#pragma unroll
        for (int s = 0; s < NSUB; ++s) {
            soff[tid][s] = o;
            o += min(scnt[tid][s], (unsigned)CAP8);
        }
        const unsigned mp = (o + 7u) & ~7u;    // pad to multiple of 8
        mtot[tid] = mp;
        for (unsigned k = o; k < mp; ++k) list[tid][k] = make_float2(0.f, 0.f);
    }
    __syncthreads();

    {   // 256-thread parallel segment copy: 4 threads per (atom, sub) segment
        const int seg = tid >> 2;              // 0..63
        const int prt = tid & 3;
        const int al = seg >> 3, s = seg & 7;
        const int n = (int)min(scnt[al][s], (unsigned)CAP8);
        const float2* src = rec + ((size_t)(mol * NSUB + s) * NATOM + (ra0 + al)) * CAP8;
        float2* dst = &list[al][soff[al][s]];
        const int k0 = prt * 4, k1 = min(k0 + 4, n);
        for (int k = k0; k < k1; ++k) dst[k] = src[k];
    }
    if (tid < ABLK * 3) {                      // tv: sum the 8 block-partials
        const int al = tid / 3, c = tid - al * 3;
        float s = 0.f;
#pragma unroll
        for (int sb = 0; sb < NSUB; ++sb)
            s += tv_part[((size_t)(mol * NSUB + sb) * NATOM + (ra0 + al)) * 3 + c];
        tvv[(size_t)(a0 + al) * 3 + c] = s;
    }
    __syncthreads();

    const int lane = tid & 63;
    const int wave = tid >> 6;
    const float cb   = centers[lane];
    const float nwb2 = -widths[lane] * 1.4426950408889634f;   // fold log2(e)

#define REC1(A, dv, fv) { const unsigned f_ = __float_as_uint(fv);           \
        const float t_ = (dv) - cb;                                          \
        A = fmaf(exp2f(nwb2 * t_ * t_) * __uint_as_float(f_ & ~7u),          \
                 cemb[((f_ & 7u) << 6) | lane], A); }

    for (int al = wave; al < ABLK; al += 4) {  // wave handles 2 atoms
        const int m = (int)mtot[al];
        const float4* l4 = reinterpret_cast<const float4*>(list[al]);
        float acc0 = 0.f, acc1 = 0.f;
        for (int j = 0; j < m; j += 8) {
            const float4 q0 = l4[(j >> 1) + 0];
            const float4 q1 = l4[(j >> 1) + 1];
            const float4 q2 = l4[(j >> 1) + 2];
            const float4 q3 = l4[(j >> 1) + 3];
            REC1(acc0, q0.x, q0.y) REC1(acc1, q0.z, q0.w)
            REC1(acc0, q1.x, q1.y) REC1(acc1, q1.z, q1.w)
            REC1(acc0, q2.x, q2.y) REC1(acc1, q2.z, q2.w)
            REC1(acc0, q3.x, q3.y) REC1(acc1, q3.z, q3.w)
        }
        dens_bf[(size_t)(a0 + al) * NB + lane] = f2bf(acc0 + acc1);
    }
#undef REC1
}

// ---------------------------------------------------------------------------
// K3 nn via MFMA: 256 blocks x 256 thr; block = 64 atoms, wave = 16-atom
// M-tile x full N=256. h = dens(bf16) @ W1(bf16,LDS-transposed) in f32 accum;
// silu*W2 on C-frags; cross-lane reduce over j; partial dipole per block.
// No per-thread weight arrays -> ~45 VGPR, allocator has nothing to demote
// (R5-R13's w1r[64] war: 52 VGPR->L2 reload storm, or 256 VGPR->occ 10%).
// Layouts: C col=lane&15,row=(lane>>4)*4+reg [m89]; A/B row=l&15,
// k=(l>>4)*8+0..7; mfma(X,Y)=X.Y^T with C-rows from X.
// ---------------------------------------------------------------------------
__global__ __launch_bounds__(256) void nn_kernel(
    const unsigned short* __restrict__ dens_bf, const float* __restrict__ tvv,
    const float* __restrict__ W1, const float* __restrict__ b1,
    const float* __restrict__ W2, const float* __restrict__ b2,
    float* __restrict__ dip_part)
{
    __shared__ __align__(16) unsigned short w1t[HIDDEN * 72];  // 36 KB, pad 64->72
    __shared__ float b1_l[HIDDEN], w2_l[HIDDEN];
    __shared__ float sred[4][4][3];

    const int tid = threadIdx.x;

    for (int i = tid; i < NB * HIDDEN; i += 256) {     // stage W1^T as bf16
        const int k = i >> 8, j = i & 255;             // coalesced f32 reads
        w1t[j * 72 + k] = f2bf(W1[i]);
    }
    if (tid < HIDDEN) { b1_l[tid] = b1[tid]; w2_l[tid] = W2[tid]; }
    __syncthreads();

    const int lane = tid & 63;
    const int wave = tid >> 6;
    const int fr   = lane & 15;        // frag row (atom) / col (j) index
    const int fg   = lane >> 4;        // frag k-group
    const int a0w  = blockIdx.x * 64 + wave * 16;      // wave's 16 atoms

    bf16x8 afr[2];                     // A-frags: 2 K-chunks of this lane's row
#pragma unroll
    for (int kk = 0; kk < 2; ++kk)
        afr[kk] = *reinterpret_cast<const bf16x8*>(
            dens_bf + (size_t)(a0w + fr) * NB + kk * 32 + fg * 8);

    float sdip[4] = {0.f, 0.f, 0.f, 0.f};
#pragma unroll
    for (int nt = 0; nt < 16; ++nt) {                  // N-tiles of 16 j's
        const bf16x8 bf0 = *reinterpret_cast<const bf16x8*>(
            &w1t[(nt * 16 + fr) * 72 + 0 + fg * 8]);
        const bf16x8 bf1 = *reinterpret_cast<const bf16x8*>(
            &w1t[(nt * 16 + fr) * 72 + 32 + fg * 8]);
        f32x4 acc = {0.f, 0.f, 0.f, 0.f};
        acc = __builtin_amdgcn_mfma_f32_16x16x32_bf16(afr[0], bf0, acc, 0, 0, 0);
        acc = __builtin_amdgcn_mfma_f32_16x16x32_bf16(afr[1], bf1, acc, 0, 0, 0);
        const int j = nt * 16 + fr;                    // this lane's column
        const float b1v = b1_l[j], w2v = w2_l[j];
#pragma unroll
        for (int i = 0; i < 4; ++i) {                  // silu * W2, accumulate
            const float h = acc[i] + b1v;
            sdip[i] += (h / (1.f + __expf(-h))) * w2v;
        }
    }
#pragma unroll
    for (int off = 1; off < 16; off <<= 1) {           // reduce over j-cols
#pragma unroll
        for (int i = 0; i < 4; ++i) sdip[i] += __shfl_xor(sdip[i], off);
    }
    if (fr == 0) {                                     // rows a0w + fg*4 + i
        const float b2v = b2[0];
        float px = 0.f, py = 0.f, pz = 0.f;
#pragma unroll
        for (int i = 0; i < 4; ++i) {
            const int a = a0w + fg * 4 + i;
            const float out = sdip[i] + b2v;
            px += out * tvv[a * 3 + 0];
            py += out * tvv[a * 3 + 1];
            pz += out * tvv[a * 3 + 2];
        }
        sred[wave][fg][0] = px; sred[wave][fg][1] = py; sred[wave][fg][2] = pz;
    }
    __syncthreads();
    if (tid < 3) {
        float s = 0.f;
#pragma unroll
        for (int w = 0; w < 4; ++w)
#pragma unroll
            for (int g = 0; g < 4; ++g) s += sred[w][g][tid];
        dip_part[blockIdx.x * 3 + tid] = s;
    }
}

// ---------------------------------------------------------------------------
// K4 dipfinal: 8 nn-block partials per molecule.
// ---------------------------------------------------------------------------
__global__ __launch_bounds__(128) void dipfinal_kernel(
    const float* __restrict__ dip_part, float* __restrict__ dipole)
{
    const int t = threadIdx.x;
    if (t < NMOL * 3) {
        const int m = t / 3, c = t - m * 3;
        float s = 0.f;
#pragma unroll
        for (int k = 0; k < 8; ++k) s += dip_part[(m * 8 + k) * 3 + c];
        dipole[t] = s;
    }
}

// ---------------------------------------------------------------------------
extern "C" void kernel_launch(void* const* d_in, const int* in_sizes, int n_in,
                              void* d_out, int out_size, void* d_ws, size_t ws_size,
                              hipStream_t stream)
{
    const float* cart       = (const float*)d_in[0];
    const float* shifts     = (const float*)d_in[1];
    const float* centers    = (const float*)d_in[2];
    const float* widths     = (const float*)d_in[3];
    const float* c_emb      = (const float*)d_in[4];
    const float* W1         = (const float*)d_in[5];
    const float* b1         = (const float*)d_in[6];
    const float* W2         = (const float*)d_in[7];
    const float* b2         = (const float*)d_in[8];
    const int*   species    = (const int*)d_in[10];
    const int*   atom_index = (const int*)d_in[11];

    // ws: tv_part(1.5MB) | cnt8(512KB) | dip_part(3KB) | tvv(192KB) |
    //     dens_bf(2MB) | rec(16MB)    (all 16B-aligned offsets)
    float*          tv_part  = (float*)d_ws;
    unsigned*       cnt8     = (unsigned*)(tv_part + (size_t)NMOL * NSUB * NATOM * 3);
    float*          dip_part = (float*)(cnt8 + (size_t)TOTNATOM * NSUB);
    float*          tvv      = dip_part + 256 * 3;
    unsigned short* dens_bf  = (unsigned short*)(tvv + (size_t)TOTNATOM * 3);
    float2*         rec      = (float2*)(dens_bf + (size_t)TOTNATOM * NB);
    float*          dipole   = (float*)d_out;

    hipLaunchKernelGGL(scatter_kernel, dim3(NMOL * NSUB), dim3(1024), 0, stream,
                       cart, shifts, species, atom_index, cnt8, rec, tv_part);
    hipLaunchKernelGGL(gather_kernel, dim3(TOTNATOM / ABLK), dim3(256), 0, stream,
                       cnt8, rec, centers, widths, c_emb, tv_part, dens_bf, tvv);
    hipLaunchKernelGGL(nn_kernel, dim3(TOTNATOM / 64), dim3(256), 0, stream,
                       dens_bf, tvv, W1, b1, W2, b2, dip_part);
    hipLaunchKernelGGL(dipfinal_kernel, dim3(1), dim3(128), 0, stream,
                       dip_part, dipole);
}